// Round 1
// baseline (169.693 us; speedup 1.0000x reference)
//
#include <hip/hip_runtime.h>
#include <hip/hip_bf16.h>

// u_dot_v: score[e] = dot(h[src[e]], h[dst[e]]), D=64.
// 16 lanes per edge: lane l loads float4 at feature offset l*4 from both rows,
// partial dot, then 4-step shuffle reduction within the 16-lane group.

__global__ __launch_bounds__(256) void edge_dot_kernel(
    const float* __restrict__ h,
    const int* __restrict__ src,
    const int* __restrict__ dst,
    float* __restrict__ out,
    int n_edges)
{
    int tid  = blockIdx.x * blockDim.x + threadIdx.x;
    int edge = tid >> 4;          // 16 threads per edge
    int lane = tid & 15;
    if (edge >= n_edges) return;

    int s = src[edge];
    int d = dst[edge];

    const float4* hs = reinterpret_cast<const float4*>(h + (size_t)s * 64);
    const float4* hd = reinterpret_cast<const float4*>(h + (size_t)d * 64);

    float4 a = hs[lane];
    float4 b = hd[lane];

    float sum = a.x * b.x + a.y * b.y + a.z * b.z + a.w * b.w;

    // reduce across the 16-lane group (wave64: xor shuffles stay in-group
    // because group is aligned within the wave)
    sum += __shfl_xor(sum, 1, 64);
    sum += __shfl_xor(sum, 2, 64);
    sum += __shfl_xor(sum, 4, 64);
    sum += __shfl_xor(sum, 8, 64);

    if (lane == 0) out[edge] = sum;
}

extern "C" void kernel_launch(void* const* d_in, const int* in_sizes, int n_in,
                              void* d_out, int out_size, void* d_ws, size_t ws_size,
                              hipStream_t stream)
{
    const float* h   = (const float*)d_in[0];
    const int*   src = (const int*)d_in[1];
    const int*   dst = (const int*)d_in[2];
    float*       out = (float*)d_out;

    int n_edges = in_sizes[1];          // 1,600,000
    int threads_per_edge = 16;
    int block = 256;
    long long total = (long long)n_edges * threads_per_edge;
    int grid = (int)((total + block - 1) / block);

    edge_dot_kernel<<<grid, block, 0, stream>>>(h, src, dst, out, n_edges);
}

// Round 2
// 123.168 us; speedup vs baseline: 1.3777x; 1.3777x over previous
//
#include <hip/hip_runtime.h>
#include <hip/hip_bf16.h>
#include <hip/hip_fp16.h>

// u_dot_v: score[e] = dot(h[src[e]], h[dst[e]]), D=64.
// Round 2: gather in fp16 to halve L2-miss bytes (the measured bottleneck:
// FETCH_SIZE=351MB @ 3.5TB/s fabric). Pre-pass converts h f32->f16 into d_ws
// (~8us streaming); gather kernel uses 8 lanes/edge x 16B loads (one 128B
// cacheline per row), accumulates in f32.

__global__ __launch_bounds__(256) void cvt_f32_to_f16(
    const float* __restrict__ in, __half* __restrict__ outp, int n4)
{
    int i = blockIdx.x * 256 + threadIdx.x;
    if (i >= n4) return;
    float4 v = reinterpret_cast<const float4*>(in)[i];
    union { __half2 h2[2]; uint2 u; } pk;
    pk.h2[0] = __floats2half2_rn(v.x, v.y);
    pk.h2[1] = __floats2half2_rn(v.z, v.w);
    reinterpret_cast<uint2*>(outp)[i] = pk.u;
}

__global__ __launch_bounds__(256) void edge_dot_f16(
    const __half* __restrict__ hh,
    const int* __restrict__ src,
    const int* __restrict__ dst,
    float* __restrict__ out,
    int n_edges)
{
    int tid  = blockIdx.x * 256 + threadIdx.x;
    int edge = tid >> 3;          // 8 threads per edge
    int lane = tid & 7;
    if (edge >= n_edges) return;

    int s = src[edge];
    int d = dst[edge];

    const int4* hs = reinterpret_cast<const int4*>(hh + (size_t)s * 64);
    const int4* hd = reinterpret_cast<const int4*>(hh + (size_t)d * 64);

    int4 av = hs[lane];   // 8 halves
    int4 bv = hd[lane];

    const __half2* ah = reinterpret_cast<const __half2*>(&av);
    const __half2* bh = reinterpret_cast<const __half2*>(&bv);

    float sum = 0.f;
    #pragma unroll
    for (int i = 0; i < 4; ++i) {
        float2 af = __half22float2(ah[i]);
        float2 bf = __half22float2(bh[i]);
        sum += af.x * bf.x + af.y * bf.y;
    }

    sum += __shfl_xor(sum, 1, 64);
    sum += __shfl_xor(sum, 2, 64);
    sum += __shfl_xor(sum, 4, 64);

    if (lane == 0) out[edge] = sum;
}

// Fallback (round-1 f32 kernel) in case ws_size can't hold fp16 h.
__global__ __launch_bounds__(256) void edge_dot_f32(
    const float* __restrict__ h,
    const int* __restrict__ src,
    const int* __restrict__ dst,
    float* __restrict__ out,
    int n_edges)
{
    int tid  = blockIdx.x * blockDim.x + threadIdx.x;
    int edge = tid >> 4;
    int lane = tid & 15;
    if (edge >= n_edges) return;
    int s = src[edge];
    int d = dst[edge];
    const float4* hs = reinterpret_cast<const float4*>(h + (size_t)s * 64);
    const float4* hd = reinterpret_cast<const float4*>(h + (size_t)d * 64);
    float4 a = hs[lane];
    float4 b = hd[lane];
    float sum = a.x * b.x + a.y * b.y + a.z * b.z + a.w * b.w;
    sum += __shfl_xor(sum, 1, 64);
    sum += __shfl_xor(sum, 2, 64);
    sum += __shfl_xor(sum, 4, 64);
    sum += __shfl_xor(sum, 8, 64);
    if (lane == 0) out[edge] = sum;
}

extern "C" void kernel_launch(void* const* d_in, const int* in_sizes, int n_in,
                              void* d_out, int out_size, void* d_ws, size_t ws_size,
                              hipStream_t stream)
{
    const float* h   = (const float*)d_in[0];
    const int*   src = (const int*)d_in[1];
    const int*   dst = (const int*)d_in[2];
    float*       out = (float*)d_out;

    int n_h     = in_sizes[0];          // 6,400,000 floats
    int n_edges = in_sizes[1];          // 1,600,000

    size_t f16_bytes = (size_t)n_h * sizeof(__half);

    if (ws_size >= f16_bytes) {
        __half* h16 = (__half*)d_ws;
        int n4 = n_h / 4;
        cvt_f32_to_f16<<<(n4 + 255) / 256, 256, 0, stream>>>(h, h16, n4);

        long long total = (long long)n_edges * 8;
        int grid = (int)((total + 255) / 256);
        edge_dot_f16<<<grid, 256, 0, stream>>>(h16, src, dst, out, n_edges);
    } else {
        long long total = (long long)n_edges * 16;
        int grid = (int)((total + 255) / 256);
        edge_dot_f32<<<grid, 256, 0, stream>>>(h, src, dst, out, n_edges);
    }
}

// Round 4
// 120.536 us; speedup vs baseline: 1.4078x; 1.0218x over previous
//
#include <hip/hip_runtime.h>
#include <hip/hip_bf16.h>
#include <hip/hip_fp16.h>

// u_dot_v: score[e] = dot(h[src[e]], h[dst[e]]), D=64.
// Round 4 (= round 3 + compile fix): int8 symmetric per-row quantization.
// dot = s_a*s_b * (int8 dot), integer part exact via v_dot4_i32_i8.
// Row = 64B -> halves L2-miss fabric traffic (measured bottleneck) and
// shrinks the gather working set to 6.8 MB. Non-temporal hints on streaming
// traffic use native ext_vector types (HIP_vector_type is rejected by
// __builtin_nontemporal_load).

typedef float  float4_n __attribute__((ext_vector_type(4)));
typedef int    int4_n   __attribute__((ext_vector_type(4)));

__global__ __launch_bounds__(256) void quantize_rows(
    const float* __restrict__ h,
    int* __restrict__ q,          // [n_rows * 16] packed int8x4
    float* __restrict__ scale,    // [n_rows]
    int n_rows)
{
    int tid  = blockIdx.x * 256 + threadIdx.x;
    int row  = tid >> 4;          // 16 lanes per row
    int lane = tid & 15;
    if (row >= n_rows) return;

    float4_n v = __builtin_nontemporal_load(
        reinterpret_cast<const float4_n*>(h + (size_t)row * 64) + lane);

    float m = fmaxf(fmaxf(fabsf(v.x), fabsf(v.y)), fmaxf(fabsf(v.z), fabsf(v.w)));
    m = fmaxf(m, __shfl_xor(m, 1, 64));
    m = fmaxf(m, __shfl_xor(m, 2, 64));
    m = fmaxf(m, __shfl_xor(m, 4, 64));
    m = fmaxf(m, __shfl_xor(m, 8, 64));

    float mm  = fmaxf(m, 1e-30f);
    float s   = mm / 127.0f;
    float inv = 127.0f / mm;

    int qx = __float2int_rn(v.x * inv);
    int qy = __float2int_rn(v.y * inv);
    int qz = __float2int_rn(v.z * inv);
    int qw = __float2int_rn(v.w * inv);
    int w = (qx & 0xff) | ((qy & 0xff) << 8) | ((qz & 0xff) << 16) | ((qw & 0xff) << 24);

    q[(size_t)row * 16 + lane] = w;
    if (lane == 0) scale[row] = s;
}

__device__ __forceinline__ int dot4_i8(int a, int b, int c) {
#if __has_builtin(__builtin_amdgcn_sdot4)
    return __builtin_amdgcn_sdot4(a, b, c, false);
#else
    int acc = c;
    #pragma unroll
    for (int k = 0; k < 4; ++k) {
        int av = (int)(char)(a >> (8 * k));
        int bv = (int)(char)(b >> (8 * k));
        acc += av * bv;
    }
    return acc;
#endif
}

__global__ __launch_bounds__(256) void edge_dot_i8(
    const int* __restrict__ q,
    const float* __restrict__ scale,
    const int* __restrict__ src,
    const int* __restrict__ dst,
    float* __restrict__ out,
    int n_edges)
{
    int tid  = blockIdx.x * 256 + threadIdx.x;
    int edge = tid >> 2;          // 4 lanes per edge, 16B each = 64B row
    int lane = tid & 3;
    if (edge >= n_edges) return;

    int s = __builtin_nontemporal_load(src + edge);
    int d = __builtin_nontemporal_load(dst + edge);

    const int4_n* qs = reinterpret_cast<const int4_n*>(q + (size_t)s * 16);
    const int4_n* qd = reinterpret_cast<const int4_n*>(q + (size_t)d * 16);

    int4_n a = qs[lane];
    int4_n b = qd[lane];

    int acc = 0;
    acc = dot4_i8(a.x, b.x, acc);
    acc = dot4_i8(a.y, b.y, acc);
    acc = dot4_i8(a.z, b.z, acc);
    acc = dot4_i8(a.w, b.w, acc);

    acc += __shfl_xor(acc, 1, 64);
    acc += __shfl_xor(acc, 2, 64);

    if (lane == 0) {
        float r = (float)acc * scale[s] * scale[d];
        __builtin_nontemporal_store(r, out + edge);
    }
}

// Fallback (round-1 f32 kernel) if ws can't hold the quantized table.
__global__ __launch_bounds__(256) void edge_dot_f32(
    const float* __restrict__ h,
    const int* __restrict__ src,
    const int* __restrict__ dst,
    float* __restrict__ out,
    int n_edges)
{
    int tid  = blockIdx.x * blockDim.x + threadIdx.x;
    int edge = tid >> 4;
    int lane = tid & 15;
    if (edge >= n_edges) return;
    int s = src[edge];
    int d = dst[edge];
    const float4* hs = reinterpret_cast<const float4*>(h + (size_t)s * 64);
    const float4* hd = reinterpret_cast<const float4*>(h + (size_t)d * 64);
    float4 a = hs[lane];
    float4 b = hd[lane];
    float sum = a.x * b.x + a.y * b.y + a.z * b.z + a.w * b.w;
    sum += __shfl_xor(sum, 1, 64);
    sum += __shfl_xor(sum, 2, 64);
    sum += __shfl_xor(sum, 4, 64);
    sum += __shfl_xor(sum, 8, 64);
    if (lane == 0) out[edge] = sum;
}

extern "C" void kernel_launch(void* const* d_in, const int* in_sizes, int n_in,
                              void* d_out, int out_size, void* d_ws, size_t ws_size,
                              hipStream_t stream)
{
    const float* h   = (const float*)d_in[0];
    const int*   src = (const int*)d_in[1];
    const int*   dst = (const int*)d_in[2];
    float*       out = (float*)d_out;

    int n_h     = in_sizes[0];          // 6,400,000 floats
    int n_edges = in_sizes[1];          // 1,600,000
    int n_rows  = n_h / 64;             // 100,000

    // ws layout: scale[n_rows] f32, then (256B-aligned) q[n_rows*16] int32
    size_t qoff    = ((size_t)n_rows * sizeof(float) + 255) & ~(size_t)255;
    size_t need    = qoff + (size_t)n_rows * 16 * sizeof(int);

    if (ws_size >= need) {
        float* scale = (float*)d_ws;
        int*   q     = (int*)((char*)d_ws + qoff);

        int qgrid = (n_rows * 16 + 255) / 256;
        quantize_rows<<<qgrid, 256, 0, stream>>>(h, q, scale, n_rows);

        long long total = (long long)n_edges * 4;
        int grid = (int)((total + 255) / 256);
        edge_dot_i8<<<grid, 256, 0, stream>>>(q, scale, src, dst, out, n_edges);
    } else {
        long long total = (long long)n_edges * 16;
        int grid = (int)((total + 255) / 256);
        edge_dot_f32<<<grid, 256, 0, stream>>>(h, src, dst, out, n_edges);
    }
}